// Round 1
// baseline (7498.468 us; speedup 1.0000x reference)
//
#include <hip/hip_runtime.h>
#include <math.h>

#define B_ 512
#define W_ 64
#define D_ 512
#define H_ 1024
#define NC_ 1024
#define K_ 8
#define C_ 64
#define BN_ 512
#define G3 (3*H_)

// ---------------- tiled SGEMM: C[M,N] = act(A[M,K] @ Bw[N,K]^T + bias) ----------------
// A row-major, leading dim lda. Bw row-major [N,K]. C row-major [M,N].
// ACT: 0 = none, 1 = silu
template<int ACT>
__global__ __launch_bounds__(256)
void sgemm_tn(const float* __restrict__ A, long lda,
              const float* __restrict__ Bw,
              const float* __restrict__ bias,
              float* __restrict__ C, int N, int Kdim)
{
    const int m0 = blockIdx.y * 64;
    const int n0 = blockIdx.x * 64;
    __shared__ float As[16][64];
    __shared__ float Bs[16][64];
    const int tid = threadIdx.x;
    const int r   = tid >> 2;          // 0..63
    const int kq  = (tid & 3) * 4;     // 0,4,8,12
    const int tx  = tid & 15;          // n-sub
    const int ty  = tid >> 4;          // m-sub
    float acc[4][4] = {};
    for (int k0 = 0; k0 < Kdim; k0 += 16) {
        float4 av = *reinterpret_cast<const float4*>(&A[(long)(m0 + r) * lda + k0 + kq]);
        float4 bv = *reinterpret_cast<const float4*>(&Bw[(long)(n0 + r) * Kdim + k0 + kq]);
        As[kq+0][r] = av.x; As[kq+1][r] = av.y; As[kq+2][r] = av.z; As[kq+3][r] = av.w;
        Bs[kq+0][r] = bv.x; Bs[kq+1][r] = bv.y; Bs[kq+2][r] = bv.z; Bs[kq+3][r] = bv.w;
        __syncthreads();
        #pragma unroll
        for (int kk = 0; kk < 16; ++kk) {
            float a0 = As[kk][ty*4+0], a1 = As[kk][ty*4+1];
            float a2 = As[kk][ty*4+2], a3 = As[kk][ty*4+3];
            float b0 = Bs[kk][tx*4+0], b1 = Bs[kk][tx*4+1];
            float b2 = Bs[kk][tx*4+2], b3 = Bs[kk][tx*4+3];
            acc[0][0] += a0*b0; acc[0][1] += a0*b1; acc[0][2] += a0*b2; acc[0][3] += a0*b3;
            acc[1][0] += a1*b0; acc[1][1] += a1*b1; acc[1][2] += a1*b2; acc[1][3] += a1*b3;
            acc[2][0] += a2*b0; acc[2][1] += a2*b1; acc[2][2] += a2*b2; acc[2][3] += a2*b3;
            acc[3][0] += a3*b0; acc[3][1] += a3*b1; acc[3][2] += a3*b2; acc[3][3] += a3*b3;
        }
        __syncthreads();
    }
    #pragma unroll
    for (int i = 0; i < 4; ++i) {
        #pragma unroll
        for (int j = 0; j < 4; ++j) {
            float v = acc[i][j] + bias[n0 + tx*4 + j];
            if (ACT == 1) v = v / (1.f + expf(-v));
            C[(long)(m0 + ty*4 + i) * N + n0 + tx*4 + j] = v;
        }
    }
}

// ---------------- GRU pointwise update ----------------
__global__ __launch_bounds__(256)
void gru_update(const float* __restrict__ gi, long gi_stride,
                const float* __restrict__ gh, float* __restrict__ h)
{
    int idx = blockIdx.x * 256 + threadIdx.x;   // B*H
    int b = idx >> 10;
    int j = idx & 1023;
    const float* gib = gi + (long)b * gi_stride;
    const float* ghb = gh + (long)b * G3;
    float ir = gib[j],      iz = gib[H_ + j],  inn = gib[2*H_ + j];
    float hr = ghb[j],      hz = ghb[H_ + j],  hn  = ghb[2*H_ + j];
    float rg = 1.f / (1.f + expf(-(ir + hr)));
    float zg = 1.f / (1.f + expf(-(iz + hz)));
    float ng = tanhf(inn + rg * hn);
    h[idx] = (1.f - zg) * ng + zg * h[idx];
}

// ---------------- emb row norms + zero loss slot ----------------
__global__ void emb_norm(const float* __restrict__ emb, float* __restrict__ e2,
                         float* __restrict__ loss_slot)
{
    int n = blockIdx.x * 256 + threadIdx.x;
    if (n == 0) *loss_slot = 0.f;
    if (n < NC_) {
        float s = 0.f;
        const float* e = emb + (long)n * C_;
        for (int c = 0; c < C_; ++c) s += e[c] * e[c];
        e2[n] = s;
    }
}

// ---------------- VQ argmin, one block per (b,k) ----------------
__global__ __launch_bounds__(256)
void vq_argmin(const float* __restrict__ q, const float* __restrict__ emb,
               const float* __restrict__ e2, float* __restrict__ out_f,
               int* __restrict__ out_i)
{
    int bk = blockIdx.x;
    int tid = threadIdx.x;
    __shared__ float qs[C_];
    if (tid < C_) qs[tid] = q[(long)bk * C_ + tid];
    __syncthreads();
    float best = 3.4e38f; int bi = 0;
    for (int n = tid; n < NC_; n += 256) {
        const float* e = emb + (long)n * C_;
        float dot = 0.f;
        #pragma unroll
        for (int c = 0; c < C_; ++c) dot += qs[c] * e[c];
        float d = e2[n] - 2.f * dot;
        if (d < best) { best = d; bi = n; }
    }
    __shared__ float sv[256];
    __shared__ int   si[256];
    sv[tid] = best; si[tid] = bi;
    __syncthreads();
    for (int s = 128; s > 0; s >>= 1) {
        if (tid < s) {
            float v2 = sv[tid + s]; int i2 = si[tid + s];
            if (v2 < sv[tid] || (v2 == sv[tid] && i2 < si[tid])) { sv[tid] = v2; si[tid] = i2; }
        }
        __syncthreads();
    }
    if (tid == 0) { out_f[bk] = (float)si[0]; out_i[bk] = si[0]; }
}

// ---------------- gather quantized + loss ----------------
__global__ __launch_bounds__(256)
void gather_loss(const float* __restrict__ q, const float* __restrict__ emb,
                 const int* __restrict__ idx, float* __restrict__ quant_out,
                 float* __restrict__ narr_out, float* __restrict__ loss_slot)
{
    int i = blockIdx.x * 256 + threadIdx.x;  // B*K*C
    int bk = i >> 6;
    int c  = i & 63;
    float e  = emb[(long)idx[bk] * C_ + c];
    float qv = q[i];
    quant_out[i] = e;
    narr_out[i]  = e;
    float dsq = (qv - e) * (qv - e);
    __shared__ float red[256];
    red[threadIdx.x] = dsq;
    __syncthreads();
    for (int s = 128; s > 0; s >>= 1) {
        if (threadIdx.x < s) red[threadIdx.x] += red[threadIdx.x + s];
        __syncthreads();
    }
    if (threadIdx.x == 0)
        atomicAdd(loss_slot, red[0] * (1.25f / (float)(B_ * K_ * C_)));
}

// ---------------- build u_in = concat(last_world_state, narrator) ----------------
__global__ __launch_bounds__(256)
void build_uin(const float* __restrict__ x, const float* __restrict__ narr,
               float* __restrict__ uin)
{
    int i = blockIdx.x * 256 + threadIdx.x;  // B*1024
    int b = i >> 10;
    int j = i & 1023;
    uin[i] = (j < D_) ? x[(long)b * W_ * D_ + (long)(W_ - 1) * D_ + j]
                      : narr[(long)b * BN_ + (j - D_)];
}

// ---------------- plain copy ----------------
__global__ __launch_bounds__(256)
void copy_f(const float* __restrict__ src, float* __restrict__ dst)
{
    int i = blockIdx.x * 256 + threadIdx.x;
    dst[i] = src[i];
}

extern "C" void kernel_launch(void* const* d_in, const int* in_sizes, int n_in,
                              void* d_out, int out_size, void* d_ws, size_t ws_size,
                              hipStream_t stream)
{
    (void)in_sizes; (void)n_in; (void)out_size;
    const float* x     = (const float*)d_in[0];
    const float* W_ih  = (const float*)d_in[1];
    const float* W_hh  = (const float*)d_in[2];
    const float* b_ih  = (const float*)d_in[3];
    const float* b_hh  = (const float*)d_in[4];
    const float* Wq    = (const float*)d_in[5];
    const float* bq    = (const float*)d_in[6];
    const float* emb   = (const float*)d_in[7];
    const float* uW1   = (const float*)d_in[8];
    const float* ub1   = (const float*)d_in[9];
    const float* uW2   = (const float*)d_in[10];
    const float* ub2   = (const float*)d_in[11];
    const float* pW1   = (const float*)d_in[12];
    const float* pb1   = (const float*)d_in[13];
    const float* pW2   = (const float*)d_in[14];
    const float* pb2   = (const float*)d_in[15];

    float* ws = (float*)d_ws;
    const long off_h      = 0;                       // B*H
    const long off_gh     = off_h   + (long)B_*H_;   // B*3H
    const long off_gi     = off_gh  + (long)B_*G3;   // B*3H (fallback)
    const long off_q      = off_gi  + (long)B_*G3;   // B*BN
    const long off_e2     = off_q   + (long)B_*BN_;  // NC
    const long off_idx    = off_e2  + NC_;           // B*K ints
    const long off_uin    = off_idx + (long)B_*K_;   // B*1024
    const long off_t1     = off_uin + (long)B_*(D_+BN_); // B*H
    const long off_h1     = off_t1  + (long)B_*H_;   // B*H
    const long off_gi_all = off_h1  + (long)B_*H_;   // B*W*3H (optional)
    const long end_precomp = off_gi_all + (long)B_*W_*G3;

    const bool precomp = (ws_size >= (size_t)end_precomp * sizeof(float));

    float* h      = ws + off_h;
    float* gh     = ws + off_gh;
    float* gi     = ws + off_gi;
    float* q      = ws + off_q;
    float* e2     = ws + off_e2;
    int*   idx_i  = (int*)(ws + off_idx);
    float* uin    = ws + off_uin;
    float* t1     = ws + off_t1;
    float* h1     = ws + off_h1;
    float* gi_all = ws + off_gi_all;

    float* out = (float*)d_out;
    const long o_idx   = 0;
    const long o_quant = o_idx   + (long)B_*K_;
    const long o_narr  = o_quant + (long)B_*K_*C_;
    const long o_unc   = o_narr  + (long)B_*BN_;
    const long o_pred  = o_unc   + (long)B_*H_;
    const long o_loss  = o_pred  + (long)B_*BN_;
    const long o_lh    = o_loss  + 1;

    hipMemsetAsync(h, 0, (size_t)B_ * H_ * sizeof(float), stream);
    emb_norm<<<4, 256, 0, stream>>>(emb, e2, out + o_loss);

    if (precomp) {
        // gi_all[b*W+w][:] = x[b,w,:] @ W_ih^T + b_ih  — one big GEMM M=B*W
        sgemm_tn<0><<<dim3(G3/64, (B_*W_)/64), 256, 0, stream>>>(
            x, D_, W_ih, b_ih, gi_all, G3, D_);
    }

    for (int w = 0; w < W_; ++w) {
        if (!precomp) {
            sgemm_tn<0><<<dim3(G3/64, B_/64), 256, 0, stream>>>(
                x + (long)w * D_, (long)W_ * D_, W_ih, b_ih, gi, G3, D_);
        }
        sgemm_tn<0><<<dim3(G3/64, B_/64), 256, 0, stream>>>(
            h, H_, W_hh, b_hh, gh, G3, H_);
        const float* gip = precomp ? (gi_all + (long)w * G3) : gi;
        long gist        = precomp ? (long)W_ * G3 : (long)G3;
        gru_update<<<(B_*H_)/256, 256, 0, stream>>>(gip, gist, gh, h);
    }

    // queries = h @ Wq^T + bq
    sgemm_tn<0><<<dim3(BN_/64, B_/64), 256, 0, stream>>>(h, H_, Wq, bq, q, BN_, H_);

    vq_argmin<<<B_*K_, 256, 0, stream>>>(q, emb, e2, out + o_idx, idx_i);
    gather_loss<<<(B_*K_*C_)/256, 256, 0, stream>>>(
        q, emb, idx_i, out + o_quant, out + o_narr, out + o_loss);

    build_uin<<<(B_*(D_+BN_))/256, 256, 0, stream>>>(x, out + o_narr, uin);

    // uncertainty = silu(u_in @ uW1^T + ub1) @ uW2^T + ub2
    sgemm_tn<1><<<dim3(H_/64, B_/64), 256, 0, stream>>>(uin, D_+BN_, uW1, ub1, h1, H_, D_+BN_);
    sgemm_tn<0><<<dim3(H_/64, B_/64), 256, 0, stream>>>(h1, H_, uW2, ub2, out + o_unc, H_, H_);

    // predicted = silu(narr @ pW1^T + pb1) @ pW2^T + pb2
    sgemm_tn<1><<<dim3(H_/64, B_/64), 256, 0, stream>>>(out + o_narr, BN_, pW1, pb1, t1, H_, BN_);
    sgemm_tn<0><<<dim3(BN_/64, B_/64), 256, 0, stream>>>(t1, H_, pW2, pb2, out + o_pred, BN_, H_);

    copy_f<<<(B_*H_)/256, 256, 0, stream>>>(h, out + o_lh);
}

// Round 2
// 2704.595 us; speedup vs baseline: 2.7725x; 2.7725x over previous
//
#include <hip/hip_runtime.h>
#include <math.h>

#define B_ 512
#define W_ 64
#define D_ 512
#define H_ 1024
#define NC_ 1024
#define K_ 8
#define C_ 64
#define BN_ 512
#define G3 (3*H_)

typedef unsigned short u16;
typedef __attribute__((ext_vector_type(8))) short bf16x8;
typedef __attribute__((ext_vector_type(4))) float f32x4;

__device__ __forceinline__ float bf_up(u16 h) { return __uint_as_float(((unsigned)h) << 16); }
__device__ __forceinline__ u16 bf_rn(float x) {
    unsigned u = __float_as_uint(x);
    return (u16)((u + 0x7FFFu + ((u >> 16) & 1u)) >> 16);
}

// convert 8 fp32 -> 8 (hi,lo) bf16 pairs, store as two 16B LDS writes
__device__ __forceinline__ void cvt_store8(u16* ph, u16* pl, float4 x, float4 y) {
    float v[8] = {x.x, x.y, x.z, x.w, y.x, y.y, y.z, y.w};
    union { u16 s[8]; uint4 u; } Hh, Ll;
    #pragma unroll
    for (int i = 0; i < 8; ++i) {
        unsigned ub = __float_as_uint(v[i]);
        u16 hi = (u16)(ub >> 16);                 // truncation
        float rem = v[i] - bf_up(hi);
        Hh.s[i] = hi;
        Ll.s[i] = bf_rn(rem);
    }
    *(uint4*)ph = Hh.u;
    *(uint4*)pl = Ll.u;
}

struct GArgs {
    const float* A;  long lda;     // fp32 A [M][K]
    const float* Bw;               // fp32 B [N][K] (row-major, used when !BPRE)
    const u16* Bhi;  const u16* Blo; // pre-split B (used when BPRE)
    const float* bias;             // [N]
    float* C;  long ldc;
    int K;
};

// ---- MFMA hi/lo GEMM core: tile M64 x N128, BK=32, 256 threads (4 waves) ----
// wave w covers n-strip [w*32, w*32+32): 4 m-frags x 2 n-frags of 16x16x32
template<int ACT, int BPRE>
__device__ __forceinline__ void gemm_core(const GArgs g, int bx, int by, u16* lds)
{
    u16* Ah = lds;            // [64][40]
    u16* Al = lds + 2560;
    u16* Bh = lds + 5120;     // [128][40]
    u16* Bl = lds + 10240;
    const int tid = threadIdx.x;
    const int l = tid & 63, w = tid >> 6;
    const int m0 = by * 64, n0 = bx * 128;
    const int sr = tid >> 2, sc = (tid & 3) * 8;

    const float* Ap = g.A + (long)(m0 + sr) * g.lda + sc;
    const float* Bp = 0; const u16 *Bph = 0, *Bpl = 0;
    if (BPRE) { Bph = g.Bhi + (long)(n0 + sr) * g.K + sc; Bpl = g.Blo + (long)(n0 + sr) * g.K + sc; }
    else      { Bp  = g.Bw  + (long)(n0 + sr) * g.K + sc; }
    const long Bstep = (long)64 * g.K;
    const int sA = sr * 40 + sc;
    const int sB1 = (sr + 64) * 40 + sc;

    f32x4 acc[4][2] = {};

    for (int k0 = 0; k0 < g.K; k0 += 32) {
        float4 a0 = *(const float4*)(Ap + k0);
        float4 a1 = *(const float4*)(Ap + k0 + 4);
        float4 b0, b1, b2, b3; uint4 h0, h1v, l0v, l1v;
        if (BPRE) {
            h0  = *(const uint4*)(Bph + k0);          l0v = *(const uint4*)(Bpl + k0);
            h1v = *(const uint4*)(Bph + Bstep + k0);  l1v = *(const uint4*)(Bpl + Bstep + k0);
        } else {
            b0 = *(const float4*)(Bp + k0);          b1 = *(const float4*)(Bp + k0 + 4);
            b2 = *(const float4*)(Bp + Bstep + k0);  b3 = *(const float4*)(Bp + Bstep + k0 + 4);
        }
        __syncthreads();   // previous iteration's frag reads complete
        cvt_store8(Ah + sA, Al + sA, a0, a1);
        if (BPRE) {
            *(uint4*)(Bh + sA) = h0;   *(uint4*)(Bl + sA) = l0v;
            *(uint4*)(Bh + sB1) = h1v; *(uint4*)(Bl + sB1) = l1v;
        } else {
            cvt_store8(Bh + sA, Bl + sA, b0, b1);
            cvt_store8(Bh + sB1, Bl + sB1, b2, b3);
        }
        __syncthreads();

        const int fr = (l & 15) * 40 + (l >> 4) * 8;
        bf16x8 ah[4], al[4], bh[2], bl[2];
        #pragma unroll
        for (int mt = 0; mt < 4; ++mt) {
            ah[mt] = *(const bf16x8*)(Ah + mt * 640 + fr);
            al[mt] = *(const bf16x8*)(Al + mt * 640 + fr);
        }
        #pragma unroll
        for (int nt = 0; nt < 2; ++nt) {
            bh[nt] = *(const bf16x8*)(Bh + (w * 32 + nt * 16) * 40 + fr);
            bl[nt] = *(const bf16x8*)(Bl + (w * 32 + nt * 16) * 40 + fr);
        }
        #pragma unroll
        for (int mt = 0; mt < 4; ++mt)
            #pragma unroll
            for (int nt = 0; nt < 2; ++nt) {
                acc[mt][nt] = __builtin_amdgcn_mfma_f32_16x16x32_bf16(ah[mt], bh[nt], acc[mt][nt], 0, 0, 0);
                acc[mt][nt] = __builtin_amdgcn_mfma_f32_16x16x32_bf16(ah[mt], bl[nt], acc[mt][nt], 0, 0, 0);
                acc[mt][nt] = __builtin_amdgcn_mfma_f32_16x16x32_bf16(al[mt], bh[nt], acc[mt][nt], 0, 0, 0);
            }
    }

    #pragma unroll
    for (int mt = 0; mt < 4; ++mt)
        #pragma unroll
        for (int nt = 0; nt < 2; ++nt) {
            int n = n0 + w * 32 + nt * 16 + (l & 15);
            float bv = g.bias[n];
            #pragma unroll
            for (int r = 0; r < 4; ++r) {
                int m = m0 + mt * 16 + (l >> 4) * 4 + r;
                float v = acc[mt][nt][r] + bv;
                if (ACT == 1) v = v / (1.f + expf(-v));
                g.C[(long)m * g.ldc + n] = v;
            }
        }
}

template<int ACT, int BPRE>
__global__ __launch_bounds__(256)
void hilo_gemm(GArgs g) {
    __shared__ u16 lds[15360];
    gemm_core<ACT, BPRE>(g, blockIdx.x, blockIdx.y, lds);
}

// one launch per GRU step: z=0 computes gh = h @ W_hh^T, z=1 computes gi = x_w @ W_ih^T
template<int BPRE>
__global__ __launch_bounds__(256)
void gru_dual(GArgs g0, GArgs g1) {
    __shared__ u16 lds[15360];
    if (blockIdx.z == 0) gemm_core<0, BPRE>(g0, blockIdx.x, blockIdx.y, lds);
    else                 gemm_core<0, BPRE>(g1, blockIdx.x, blockIdx.y, lds);
}

// ---------------- fp32 -> hi/lo split (weights, once per launch) ----------------
__global__ __launch_bounds__(256)
void to_hilo(const float* __restrict__ src, u16* __restrict__ hi, u16* __restrict__ lo, long n8) {
    long i = (long)blockIdx.x * 256 + threadIdx.x;
    if (i >= n8) return;
    float4 a = ((const float4*)src)[2 * i];
    float4 b = ((const float4*)src)[2 * i + 1];
    union { u16 s[8]; uint4 u; } Hh, Ll;
    float v[8] = {a.x, a.y, a.z, a.w, b.x, b.y, b.z, b.w};
    #pragma unroll
    for (int j = 0; j < 8; ++j) {
        unsigned ub = __float_as_uint(v[j]);
        u16 h = (u16)(ub >> 16);
        Hh.s[j] = h;
        Ll.s[j] = bf_rn(v[j] - bf_up(h));
    }
    ((uint4*)hi)[i] = Hh.u;
    ((uint4*)lo)[i] = Ll.u;
}

// ---------------- GRU pointwise update ----------------
__global__ __launch_bounds__(256)
void gru_update(const float* __restrict__ gi, const float* __restrict__ gh,
                float* __restrict__ h)
{
    int idx = blockIdx.x * 256 + threadIdx.x;   // B*H
    int b = idx >> 10;
    int j = idx & 1023;
    const float* gib = gi + (long)b * G3;
    const float* ghb = gh + (long)b * G3;
    float ir = gib[j], iz = gib[H_ + j], inn = gib[2 * H_ + j];
    float hr = ghb[j], hz = ghb[H_ + j], hn  = ghb[2 * H_ + j];
    float rg = 1.f / (1.f + expf(-(ir + hr)));
    float zg = 1.f / (1.f + expf(-(iz + hz)));
    float ng = tanhf(inn + rg * hn);
    h[idx] = (1.f - zg) * ng + zg * h[idx];
}

// ---------------- emb row norms + zero loss slot ----------------
__global__ void emb_norm(const float* __restrict__ emb, float* __restrict__ e2,
                         float* __restrict__ loss_slot)
{
    int n = blockIdx.x * 256 + threadIdx.x;
    if (n == 0) *loss_slot = 0.f;
    if (n < NC_) {
        const float4* e4 = (const float4*)(emb + (long)n * C_);
        float s = 0.f;
        #pragma unroll
        for (int c = 0; c < 16; ++c) { float4 e = e4[c]; s += e.x*e.x + e.y*e.y + e.z*e.z + e.w*e.w; }
        e2[n] = s;
    }
}

// ---------------- VQ argmin, one block per (b,k), float4 dots ----------------
__global__ __launch_bounds__(256)
void vq_argmin(const float* __restrict__ q, const float* __restrict__ emb,
               const float* __restrict__ e2, float* __restrict__ out_f,
               int* __restrict__ out_i)
{
    int bk = blockIdx.x;
    int tid = threadIdx.x;
    __shared__ float4 qs[16];
    if (tid < 16) qs[tid] = ((const float4*)(q + (long)bk * C_))[tid];
    __syncthreads();
    float best = 3.4e38f; int bi = 0;
    for (int n = tid; n < NC_; n += 256) {
        const float4* e4 = (const float4*)(emb + (long)n * C_);
        float dot = 0.f;
        #pragma unroll
        for (int c = 0; c < 16; ++c) {
            float4 ev = e4[c], qv = qs[c];
            dot += ev.x*qv.x + ev.y*qv.y + ev.z*qv.z + ev.w*qv.w;
        }
        float d = e2[n] - 2.f * dot;
        if (d < best) { best = d; bi = n; }
    }
    __shared__ float sv[256];
    __shared__ int   si[256];
    sv[tid] = best; si[tid] = bi;
    __syncthreads();
    for (int s = 128; s > 0; s >>= 1) {
        if (tid < s) {
            float v2 = sv[tid + s]; int i2 = si[tid + s];
            if (v2 < sv[tid] || (v2 == sv[tid] && i2 < si[tid])) { sv[tid] = v2; si[tid] = i2; }
        }
        __syncthreads();
    }
    if (tid == 0) { out_f[bk] = (float)si[0]; out_i[bk] = si[0]; }
}

// ---------------- gather quantized + loss ----------------
__global__ __launch_bounds__(256)
void gather_loss(const float* __restrict__ q, const float* __restrict__ emb,
                 const int* __restrict__ idx, float* __restrict__ quant_out,
                 float* __restrict__ narr_out, float* __restrict__ loss_slot)
{
    int i = blockIdx.x * 256 + threadIdx.x;  // B*K*C
    int bk = i >> 6;
    int c  = i & 63;
    float e  = emb[(long)idx[bk] * C_ + c];
    float qv = q[i];
    quant_out[i] = e;
    narr_out[i]  = e;
    float dsq = (qv - e) * (qv - e);
    __shared__ float red[256];
    red[threadIdx.x] = dsq;
    __syncthreads();
    for (int s = 128; s > 0; s >>= 1) {
        if (threadIdx.x < s) red[threadIdx.x] += red[threadIdx.x + s];
        __syncthreads();
    }
    if (threadIdx.x == 0)
        atomicAdd(loss_slot, red[0] * (1.25f / (float)(B_ * K_ * C_)));
}

// ---------------- build u_in = concat(last_world_state, narrator) ----------------
__global__ __launch_bounds__(256)
void build_uin(const float* __restrict__ x, const float* __restrict__ narr,
               float* __restrict__ uin)
{
    int i = blockIdx.x * 256 + threadIdx.x;  // B*1024
    int b = i >> 10;
    int j = i & 1023;
    uin[i] = (j < D_) ? x[(long)b * W_ * D_ + (long)(W_ - 1) * D_ + j]
                      : narr[(long)b * BN_ + (j - D_)];
}

__global__ __launch_bounds__(256)
void copy_f(const float* __restrict__ src, float* __restrict__ dst)
{
    int i = blockIdx.x * 256 + threadIdx.x;
    dst[i] = src[i];
}

extern "C" void kernel_launch(void* const* d_in, const int* in_sizes, int n_in,
                              void* d_out, int out_size, void* d_ws, size_t ws_size,
                              hipStream_t stream)
{
    (void)in_sizes; (void)n_in; (void)out_size;
    const float* x     = (const float*)d_in[0];
    const float* W_ih  = (const float*)d_in[1];
    const float* W_hh  = (const float*)d_in[2];
    const float* b_ih  = (const float*)d_in[3];
    const float* b_hh  = (const float*)d_in[4];
    const float* Wq    = (const float*)d_in[5];
    const float* bq    = (const float*)d_in[6];
    const float* emb   = (const float*)d_in[7];
    const float* uW1   = (const float*)d_in[8];
    const float* ub1   = (const float*)d_in[9];
    const float* uW2   = (const float*)d_in[10];
    const float* ub2   = (const float*)d_in[11];
    const float* pW1   = (const float*)d_in[12];
    const float* pb1   = (const float*)d_in[13];
    const float* pW2   = (const float*)d_in[14];
    const float* pb2   = (const float*)d_in[15];

    float* ws = (float*)d_ws;
    // float region (known-safe footprint ~15.8 MB)
    float* h    = ws;                       // 524288
    float* gh   = ws + 524288;              // 1572864
    float* gis  = ws + 2097152;             // 1572864
    float* q    = ws + 3670016;             // 262144
    float* e2   = ws + 3932160;             // 1024
    int*   idxi = (int*)(ws + 3933184);     // 4096
    const long FLOAT_WORDS = 3937280;
    // aliases (only live after the GRU loop)
    float* uin = gh;                        // 524288
    float* h1  = gh + 524288;               // 524288
    float* t1  = gis;                       // 524288

    // optional pre-split weight region
    u16* wsu = (u16*)((char*)d_ws + FLOAT_WORDS * sizeof(float));
    u16* whh_h = wsu;            u16* whh_l = wsu + 3145728;
    u16* wih_h = wsu + 6291456;  u16* wih_l = wsu + 7864320;
    u16* wq_h  = wsu + 9437184;  u16* wq_l  = wsu + 9961472;
    u16* uw1_h = wsu + 10485760; u16* uw1_l = wsu + 11534336;
    u16* uw2_h = wsu + 12582912; u16* uw2_l = wsu + 13631488;
    u16* pw1_h = wsu + 14680064; u16* pw1_l = wsu + 15204352;
    u16* pw2_h = wsu + 15728640; u16* pw2_l = wsu + 16252928;
    const size_t NEED_BPRE = FLOAT_WORDS * sizeof(float) + (size_t)16777216 * 2;
    const bool bpre = ws_size >= NEED_BPRE;

    float* out = (float*)d_out;
    const long o_idx   = 0;
    const long o_quant = o_idx   + (long)B_ * K_;
    const long o_narr  = o_quant + (long)B_ * K_ * C_;
    const long o_unc   = o_narr  + (long)B_ * BN_;
    const long o_pred  = o_unc   + (long)B_ * H_;
    const long o_loss  = o_pred  + (long)B_ * BN_;
    const long o_lh    = o_loss  + 1;

    hipMemsetAsync(h, 0, (size_t)B_ * H_ * sizeof(float), stream);
    emb_norm<<<4, 256, 0, stream>>>(emb, e2, out + o_loss);

    if (bpre) {
        auto cvt = [&](const float* s, u16* hi, u16* lo, long n) {
            long n8 = n / 8;
            to_hilo<<<(int)((n8 + 255) / 256), 256, 0, stream>>>(s, hi, lo, n8);
        };
        cvt(W_hh, whh_h, whh_l, (long)G3 * H_);
        cvt(W_ih, wih_h, wih_l, (long)G3 * D_);
        cvt(Wq,   wq_h,  wq_l,  (long)BN_ * H_);
        cvt(uW1,  uw1_h, uw1_l, (long)H_ * (D_ + BN_));
        cvt(uW2,  uw2_h, uw2_l, (long)H_ * H_);
        cvt(pW1,  pw1_h, pw1_l, (long)H_ * BN_);
        cvt(pW2,  pw2_h, pw2_l, (long)BN_ * H_);
    }

    auto mkargs = [&](const float* A, long lda, const float* Bw, const u16* Bh, const u16* Bl,
                      const float* bias, float* C, long ldc, int K) {
        GArgs g; g.A = A; g.lda = lda; g.Bw = Bw; g.Bhi = Bh; g.Blo = Bl;
        g.bias = bias; g.C = C; g.ldc = ldc; g.K = K; return g;
    };

    // ---- GRU loop: one dual-GEMM + one pointwise update per step ----
    for (int w = 0; w < W_; ++w) {
        GArgs g0 = mkargs(h, H_, W_hh, whh_h, whh_l, b_hh, gh, G3, H_);
        GArgs g1 = mkargs(x + (long)w * D_, (long)W_ * D_, W_ih, wih_h, wih_l, b_ih, gis, G3, D_);
        dim3 grid(G3 / 128, B_ / 64, 2);
        if (bpre) gru_dual<1><<<grid, 256, 0, stream>>>(g0, g1);
        else      gru_dual<0><<<grid, 256, 0, stream>>>(g0, g1);
        gru_update<<<(B_ * H_) / 256, 256, 0, stream>>>(gis, gh, h);
    }

    auto gemm = [&](int act, GArgs g, int N, int M) {
        dim3 grid(N / 128, M / 64);
        if (bpre) {
            if (act == 1) hilo_gemm<1, 1><<<grid, 256, 0, stream>>>(g);
            else          hilo_gemm<0, 1><<<grid, 256, 0, stream>>>(g);
        } else {
            if (act == 1) hilo_gemm<1, 0><<<grid, 256, 0, stream>>>(g);
            else          hilo_gemm<0, 0><<<grid, 256, 0, stream>>>(g);
        }
    };

    // queries = h @ Wq^T + bq
    gemm(0, mkargs(h, H_, Wq, wq_h, wq_l, bq, q, BN_, H_), BN_, B_);

    vq_argmin<<<B_ * K_, 256, 0, stream>>>(q, emb, e2, out + o_idx, idxi);
    gather_loss<<<(B_ * K_ * C_) / 256, 256, 0, stream>>>(
        q, emb, idxi, out + o_quant, out + o_narr, out + o_loss);

    build_uin<<<(B_ * (D_ + BN_)) / 256, 256, 0, stream>>>(x, out + o_narr, uin);

    // uncertainty = silu(u_in @ uW1^T + ub1) @ uW2^T + ub2
    gemm(1, mkargs(uin, D_ + BN_, uW1, uw1_h, uw1_l, ub1, h1, H_, D_ + BN_), H_, B_);
    gemm(0, mkargs(h1, H_, uW2, uw2_h, uw2_l, ub2, out + o_unc, H_, H_), H_, B_);

    // predicted = silu(narr @ pW1^T + pb1) @ pW2^T + pb2
    gemm(1, mkargs(out + o_narr, BN_, pW1, pw1_h, pw1_l, pb1, t1, H_, BN_), H_, B_);
    gemm(0, mkargs(t1, H_, pW2, pw2_h, pw2_l, pb2, out + o_pred, BN_, H_), BN_, B_);

    copy_f<<<(B_ * H_) / 256, 256, 0, stream>>>(h, out + o_lh);
}